// Round 6
// baseline (223.886 us; speedup 1.0000x reference)
//
#include <hip/hip_runtime.h>

// NeuralHashVoxel round 5: 2-stage spatial sort (4096-bin atomic-free counting
// sort + per-bin LDS bitonic by full 30-bit Morton) -> near-perfect Morton
// order for the gather kernel; XCD-slab swizzle kept; nt load/store for
// streaming data so tables keep L2/L3 residency.

static constexpr int      NPTS  = 1048576;
static constexpr int      LVLS  = 6;
static constexpr int      NF    = 8;
static constexpr int      TTAB  = 524288;
static constexpr unsigned BTAB  = 4194304u;          // 2^22 buckets per level
static constexpr unsigned BMASK = BTAB - 1u;
static constexpr unsigned P0 = 73856093u, P1 = 19349669u, P2 = 83492791u;

static constexpr int NBIN = 4096;        // 16^3 Morton bins, cell = 3.125
static constexpr int SB   = 256;         // sort blocks
static constexpr int PPB  = NPTS / SB;   // 4096 points per sort block
static constexpr int ITER = PPB / 256;   // 16 per thread
static constexpr int BCAP = 512;         // stage-2 per-bin capacity (avg 256)

typedef float f4 __attribute__((ext_vector_type(4)));

// ---------------- per-point computation ----------------
__device__ __forceinline__ void nhv_point(
    float qx, float qy, float qz,
    const float* __restrict__ feat, const int* __restrict__ fidx, float acc[NF])
{
    float    fx[LVLS], fy[LVLS], fz[LVLS];
    unsigned h[LVLS];
#pragma unroll
    for (int i = 0; i < LVLS; ++i) {
        const float inv = 4.0f / (float)(1 << i);    // exact pow2: q*inv == q/res
        const float sx = qx * inv, sy = qy * inv, sz = qz * inv;
        const float bx = floorf(sx), by = floorf(sy), bz = floorf(sz);
        fx[i] = sx - bx; fy[i] = sy - by; fz[i] = sz - bz;
        h[i] = (unsigned)(int)bx * P0 + (unsigned)(int)by * P1 + (unsigned)(int)bz * P2;
    }

    int id[LVLS][8];
#pragma unroll
    for (int i = 0; i < LVLS; ++i) {
        const int* __restrict__ tab = fidx + (size_t)i * BTAB;
#pragma unroll
        for (int k = 0; k < 8; ++k) {
            unsigned key = h[i];
            if (k & 4) key += P0;
            if (k & 2) key += P1;
            if (k & 1) key += P2;
            id[i][k] = tab[key & BMASK];
        }
    }

#pragma unroll
    for (int f = 0; f < NF; ++f) acc[f] = 0.0f;

#pragma unroll
    for (int i = 0; i < LVLS; ++i) {
        int mn = id[i][0];
#pragma unroll
        for (int k = 1; k < 8; ++k) mn = min(mn, id[i][k]);
        if (mn > -1) {
            const float wxv[2] = {1.0f - fx[i], fx[i]};
            const float wyv[2] = {1.0f - fy[i], fy[i]};
            const float wzv[2] = {1.0f - fz[i], fz[i]};
            const float* __restrict__ fb = feat + (size_t)i * (TTAB * NF);
#pragma unroll
            for (int k = 0; k < 8; ++k) {
                const float c = wxv[(k >> 2) & 1] * wyv[(k >> 1) & 1] * wzv[k & 1];
                const float4* p = (const float4*)(fb + (size_t)id[i][k] * NF);
                const float4 lo = p[0];
                const float4 hi = p[1];
                acc[0] += c * lo.x; acc[1] += c * lo.y;
                acc[2] += c * lo.z; acc[3] += c * lo.w;
                acc[4] += c * hi.x; acc[5] += c * hi.y;
                acc[6] += c * hi.z; acc[7] += c * hi.w;
            }
        }
    }
}

// ---------------- binning / Morton ----------------
__device__ __forceinline__ unsigned expand4(unsigned v) {
    return (v & 1u) | ((v & 2u) << 2) | ((v & 4u) << 4) | ((v & 8u) << 6);
}
__device__ __forceinline__ unsigned bin_of(float x, float y, float z) {
    unsigned bx = min(15u, (unsigned)(int)(x * 0.32f));
    unsigned by = min(15u, (unsigned)(int)(y * 0.32f));
    unsigned bz = min(15u, (unsigned)(int)(z * 0.32f));
    return expand4(bx) | (expand4(by) << 1) | (expand4(bz) << 2);
}
__device__ __forceinline__ unsigned expand10(unsigned v) {
    v = (v | (v << 16)) & 0x030000FFu;
    v = (v | (v << 8))  & 0x0300F00Fu;
    v = (v | (v << 4))  & 0x030C30C3u;
    v = (v | (v << 2))  & 0x09249249u;
    return v;
}
__device__ __forceinline__ unsigned morton30(float x, float y, float z) {
    // 10 bits/axis over [0,50): cell 0.0488
    unsigned ux = min(1023u, (unsigned)(int)(x * 20.48f));
    unsigned uy = min(1023u, (unsigned)(int)(y * 20.48f));
    unsigned uz = min(1023u, (unsigned)(int)(z * 20.48f));
    return expand10(ux) | (expand10(uy) << 1) | (expand10(uz) << 2);
}

// ---------------- sort stage 1 (no global atomics) ----------------
__global__ __launch_bounds__(256) void hist_k(const float* __restrict__ qp,
                                              unsigned* __restrict__ hist) {
    __shared__ unsigned lh[NBIN];
    const int b = blockIdx.x, t = threadIdx.x;
    for (int i = t; i < NBIN; i += 256) lh[i] = 0u;
    __syncthreads();
    const int base = b * PPB;
#pragma unroll
    for (int i = 0; i < ITER; ++i) {
        const int p = base + i * 256 + t;
        atomicAdd(&lh[bin_of(qp[3*p], qp[3*p+1], qp[3*p+2])], 1u);
    }
    __syncthreads();
    for (int i = t; i < NBIN; i += 256) hist[(size_t)b * NBIN + i] = lh[i];
}

__global__ __launch_bounds__(256) void colscan_k(unsigned* __restrict__ hist,
                                                 unsigned* __restrict__ binbase) {
    const int bin = blockIdx.x * 256 + threadIdx.x;   // 16 blocks
    unsigned run = 0;
    for (int b = 0; b < SB; ++b) {
        const unsigned v = hist[(size_t)b * NBIN + bin];
        hist[(size_t)b * NBIN + bin] = run;
        run += v;
    }
    binbase[bin] = run;
}

__global__ __launch_bounds__(256) void binscan_k(unsigned* __restrict__ binbase) {
    __shared__ unsigned tot[256];
    const int t = threadIdx.x;
    unsigned v[16];
    unsigned s = 0;
#pragma unroll
    for (int i = 0; i < 16; ++i) { v[i] = s; s += binbase[t * 16 + i]; }
    tot[t] = s;
    __syncthreads();
    for (int d = 1; d < 256; d <<= 1) {
        const unsigned x = (t >= d) ? tot[t - d] : 0u;
        __syncthreads();
        tot[t] += x;
        __syncthreads();
    }
    const unsigned cb = tot[t] - s;
#pragma unroll
    for (int i = 0; i < 16; ++i) binbase[t * 16 + i] = cb + v[i];
}

__global__ __launch_bounds__(256) void scatter_k(const float* __restrict__ qp,
                                                 const unsigned* __restrict__ hist,
                                                 const unsigned* __restrict__ binbase,
                                                 float4* __restrict__ sorted) {
    __shared__ unsigned cur[NBIN];
    const int b = blockIdx.x, t = threadIdx.x;
    for (int i = t; i < NBIN; i += 256)
        cur[i] = binbase[i] + hist[(size_t)b * NBIN + i];
    __syncthreads();
    const int base = b * PPB;
#pragma unroll
    for (int i = 0; i < ITER; ++i) {
        const int p = base + i * 256 + t;
        const float x = qp[3*p], y = qp[3*p+1], z = qp[3*p+2];
        const unsigned slot = atomicAdd(&cur[bin_of(x, y, z)], 1u);
        sorted[slot] = make_float4(x, y, z, __uint_as_float((unsigned)p));
    }
}

// ---------------- sort stage 2: per-bin LDS bitonic by 30-bit Morton -------
__global__ __launch_bounds__(256) void binsort_k(float4* __restrict__ sorted,
                                                 const unsigned* __restrict__ binbase) {
    __shared__ float4   pts[BCAP];
    __shared__ unsigned key[BCAP];
    __shared__ unsigned short pay[BCAP];

    const int bin   = blockIdx.x;
    const int t     = threadIdx.x;
    const unsigned start = binbase[bin];
    const unsigned end   = (bin < NBIN - 1) ? binbase[bin + 1] : (unsigned)NPTS;
    const int n = (int)(end - start);
    if (n <= 1 || n > BCAP) return;   // oversize bin: skip (perf-only, deterministic)

#pragma unroll
    for (int r = 0; r < BCAP / 256; ++r) {
        const int i = r * 256 + t;
        if (i < n) {
            const float4 p = sorted[start + i];
            pts[i] = p;
            key[i] = morton30(p.x, p.y, p.z);
        } else {
            key[i] = 0xFFFFFFFFu;
        }
        pay[i] = (unsigned short)i;
    }
    __syncthreads();

    // bitonic sort of BCAP (key,pay) pairs, 256 threads x 2 CE per stage
    for (int k = 2; k <= BCAP; k <<= 1) {
        for (int j = k >> 1; j > 0; j >>= 1) {
#pragma unroll
            for (int r = 0; r < BCAP / 512; ++r) {
                const int tid = r * 256 + t;
                const int i   = ((tid & ~(j - 1)) << 1) | (tid & (j - 1));
                const int p2  = i | j;
                const bool up = ((i & k) == 0);
                const unsigned ka = key[i], kb = key[p2];
                if ((ka > kb) == up) {
                    key[i] = kb; key[p2] = ka;
                    const unsigned short tmp = pay[i]; pay[i] = pay[p2]; pay[p2] = tmp;
                }
            }
            __syncthreads();
        }
    }

#pragma unroll
    for (int r = 0; r < BCAP / 256; ++r) {
        const int i = r * 256 + t;
        if (i < n) sorted[start + i] = pts[pay[i]];
    }
}

// ---------------- main kernels ----------------
__global__ __launch_bounds__(256) void nhv_sorted_k(
    const float4* __restrict__ sp, const float* __restrict__ feat,
    const int* __restrict__ fidx, float* __restrict__ out)
{
    // XCD-chunked swizzle: each XCD gets a contiguous Morton (spatial) slab.
    const int nwg = NPTS / 256;
    const int bid = blockIdx.x;
    const int swz = (bid & 7) * (nwg >> 3) + (bid >> 3);
    const int j   = swz * 256 + (int)threadIdx.x;

    const f4 s = __builtin_nontemporal_load((const f4*)sp + j);   // streaming
    float acc[NF];
    nhv_point(s.x, s.y, s.z, feat, fidx, acc);
    const unsigned n = __float_as_uint(s.w);

    f4* o = (f4*)(out + (size_t)n * NF);
    f4 lo = {acc[0], acc[1], acc[2], acc[3]};
    f4 hi = {acc[4], acc[5], acc[6], acc[7]};
    __builtin_nontemporal_store(lo, o);          // write-only, don't pollute L2/L3
    __builtin_nontemporal_store(hi, o + 1);
}

__global__ __launch_bounds__(256) void nhv_direct_k(
    const float* __restrict__ qp, const float* __restrict__ feat,
    const int* __restrict__ fidx, float* __restrict__ out)
{
    const int n = blockIdx.x * 256 + threadIdx.x;
    if (n >= NPTS) return;
    float acc[NF];
    nhv_point(qp[3*n], qp[3*n+1], qp[3*n+2], feat, fidx, acc);
    float4* o = (float4*)(out + (size_t)n * NF);
    o[0] = make_float4(acc[0], acc[1], acc[2], acc[3]);
    o[1] = make_float4(acc[4], acc[5], acc[6], acc[7]);
}

extern "C" void kernel_launch(void* const* d_in, const int* in_sizes, int n_in,
                              void* d_out, int out_size, void* d_ws, size_t ws_size,
                              hipStream_t stream) {
    const float* qp   = (const float*)d_in[0];
    const float* feat = (const float*)d_in[1];
    const int*   fidx = (const int*)d_in[2];
    float*       out  = (float*)d_out;

    const size_t ws_needed = (size_t)NPTS * 16;       // sorted buffer only

    if (ws_size >= ws_needed) {
        // hist (4 MB) + binbase (16 KB) live in d_out; main kernel fully
        // overwrites d_out afterwards (same stream, ordered) -> deterministic.
        unsigned* hist    = (unsigned*)d_out;
        unsigned* binbase = hist + (size_t)SB * NBIN;
        float4*   sorted  = (float4*)d_ws;

        hipLaunchKernelGGL(hist_k,    dim3(SB),   dim3(256), 0, stream, qp, hist);
        hipLaunchKernelGGL(colscan_k, dim3(16),   dim3(256), 0, stream, hist, binbase);
        hipLaunchKernelGGL(binscan_k, dim3(1),    dim3(256), 0, stream, binbase);
        hipLaunchKernelGGL(scatter_k, dim3(SB),   dim3(256), 0, stream, qp, hist, binbase, sorted);
        hipLaunchKernelGGL(binsort_k, dim3(NBIN), dim3(256), 0, stream, sorted, binbase);
        hipLaunchKernelGGL(nhv_sorted_k, dim3(NPTS/256), dim3(256), 0, stream,
                           sorted, feat, fidx, out);
    } else {
        hipLaunchKernelGGL(nhv_direct_k, dim3(NPTS/256), dim3(256), 0, stream,
                           qp, feat, fidx, out);
    }
}